// Round 4
// baseline (295.686 us; speedup 1.0000x reference)
//
#include <hip/hip_runtime.h>

#define LSEQ 200
#define KCAP 4
#define NVOC 100000

__device__ __forceinline__ void fma4(float4& a, float s, const float4& v) {
    a.x = fmaf(s, v.x, a.x); a.y = fmaf(s, v.y, a.y);
    a.z = fmaf(s, v.z, a.z); a.w = fmaf(s, v.w, a.w);
}

// ---------------------------------------------------------------------------
// Kernel 1: P = (E with row 0 zeroed) @ S.  Block = 256 vocab rows
// (lane = row-in-64-group, g = 4 groups/thread), wave = 16-column slice.
// S staged in LDS, read as wave-uniform ds_read_b128 broadcasts; each
// broadcast feeds 16 FMA-inst (4 rows x fma4). VGPR ~116, pinned 4 waves/EU.
// ---------------------------------------------------------------------------
__global__ __launch_bounds__(256) __attribute__((amdgpu_waves_per_eu(4, 4)))
void precompute_P(const float* __restrict__ E, const float* __restrict__ S,
                  float* __restrict__ P)
{
    __shared__ __align__(16) float4 Sl4[1024];     // S[e][4j..4j+3] = Sl4[e*16+j]
    const int tid = threadIdx.x;
    #pragma unroll
    for (int t = tid; t < 1024; t += 256) Sl4[t] = ((const float4*)S)[t];
    __syncthreads();

    const int lane = tid & 63;
    const int wv   = tid >> 6;                     // column slice [wv*16, wv*16+16)
    const int base = blockIdx.x * 256;

    int  row[4]; bool ok[4];
    #pragma unroll
    for (int g = 0; g < 4; g++) { row[g] = base + g * 64 + lane; ok[g] = row[g] < NVOC; }

    const float4* __restrict__ E4 = (const float4*)E;
    float4 acc[4][4];
    #pragma unroll
    for (int g = 0; g < 4; g++)
        #pragma unroll
        for (int j = 0; j < 4; j++) acc[g][j] = make_float4(0.f, 0.f, 0.f, 0.f);

    #pragma unroll 1
    for (int ec = 0; ec < 16; ec++) {              // e-chunks of 4
        float4 er[4];
        #pragma unroll
        for (int g = 0; g < 4; g++) er[g] = E4[(size_t)(ok[g] ? row[g] : 0) * 16 + ec];
        #pragma unroll
        for (int u = 0; u < 4; u++) {
            const float4* Se = Sl4 + (ec * 4 + u) * 16 + wv * 4;  // uniform -> bcast
            float4 s0 = Se[0], s1 = Se[1], s2 = Se[2], s3 = Se[3];
            #pragma unroll
            for (int g = 0; g < 4; g++) {
                float ev = ((const float*)&er[g])[u];
                fma4(acc[g][0], ev, s0); fma4(acc[g][1], ev, s1);
                fma4(acc[g][2], ev, s2); fma4(acc[g][3], ev, s3);
            }
        }
    }
    #pragma unroll
    for (int g = 0; g < 4; g++) {
        if (!ok[g]) continue;
        float4* Pr = (float4*)P + (size_t)row[g] * 16 + wv * 4;
        if (row[g] == 0) {
            Pr[0] = Pr[1] = Pr[2] = Pr[3] = make_float4(0.f, 0.f, 0.f, 0.f);
        } else {
            Pr[0] = acc[g][0]; Pr[1] = acc[g][1]; Pr[2] = acc[g][2]; Pr[3] = acc[g][3];
        }
    }
}

// ---------------------------------------------------------------------------
// Kernel 2: one batch row per block. hisP in registers only; phase D via
// 16-lane butterflies. waves_per_eu pinned (4,4): VGPR budget 128 -> no
// scratch spill (R3's 64-VGPR cap spilled 74 MB), 4 blocks/CU.
// ---------------------------------------------------------------------------
__global__ __launch_bounds__(256) __attribute__((amdgpu_waves_per_eu(4, 4)))
void mind_row(
    const int*   __restrict__ his, const float* __restrict__ P,
    const float* __restrict__ B0,  const float* __restrict__ W1,
    const float* __restrict__ b1,  const float* __restrict__ W2,
    const float* __restrict__ b2,  float* __restrict__ out)
{
    __shared__ __align__(16) float  W4[LSEQ * 4];       // W4[l*4+k]
    __shared__ __align__(16) float  Bm[KCAP * LSEQ];
    __shared__ __align__(16) float  caps4[64 * 4];      // caps4[d*4+k]
    __shared__ __align__(16) float4 capsT4[KCAP * 16];  // capsT4[k*16+j]
    __shared__ __align__(16) float4 part4[16 * 17];     // [(w*4+k)*17 + r]
    __shared__ __align__(16) float4 h44[256];           // MLP hidden
    __shared__ float bigneg[LSEQ];
    __shared__ int   idxs[LSEQ];

    const int b = blockIdx.x, tid = threadIdx.x;
    const int lane = tid & 63, wv = tid >> 6;
    const int q = lane >> 4, r = lane & 15;

    for (int l = tid; l < LSEQ; l += 256) {
        int id = his[b * LSEQ + l];
        idxs[l]   = id;
        bigneg[l] = (id != 0) ? 0.f : -1e30f;
    }
    for (int t = tid; t < KCAP * LSEQ; t += 256) Bm[t] = B0[t];
    __syncthreads();

    // Gather: wave wv covers l in [wv*50, wv*50+50); thread (q,r): l=base+4i+q,
    // d-chunk = r. 13 b128 global loads, registers only.
    float4 hp4[13];
    const float4* P4 = (const float4*)P;
    #pragma unroll
    for (int i = 0; i < 13; i++) {
        int  l     = wv * 50 + i * 4 + q;
        bool valid = (i < 12) || (q < 2);               // 12*4+2 = 50
        int  lc    = valid ? l : 0;
        float4 vv  = P4[(size_t)idxs[lc] * 16 + r];
        if (!valid) vv = make_float4(0.f, 0.f, 0.f, 0.f);
        hp4[i] = vv;
    }

    for (int rr = 0; rr < 3; rr++) {
        // A: masked softmax over l; capsule k = wv (one wave per capsule)
        {
            const float* Bk = Bm + wv * LSEQ;
            float x0 = Bk[lane]       + bigneg[lane];
            float x1 = Bk[lane + 64]  + bigneg[lane + 64];
            float x2 = Bk[lane + 128] + bigneg[lane + 128];
            float x3 = (lane < 8) ? (Bk[lane + 192] + bigneg[lane + 192]) : -3.0e38f;
            float m = fmaxf(fmaxf(x0, x1), fmaxf(x2, x3));
            #pragma unroll
            for (int off = 32; off; off >>= 1) m = fmaxf(m, __shfl_xor(m, off, 64));
            float e0 = __expf(x0 - m), e1 = __expf(x1 - m), e2 = __expf(x2 - m);
            float e3 = (lane < 8) ? __expf(x3 - m) : 0.f;
            float s = e0 + e1 + e2 + e3;
            #pragma unroll
            for (int off = 32; off; off >>= 1) s += __shfl_xor(s, off, 64);
            float inv = 1.f / s;
            W4[lane * 4 + wv]         = e0 * inv;
            W4[(lane + 64) * 4 + wv]  = e1 * inv;
            W4[(lane + 128) * 4 + wv] = e2 * inv;
            if (lane < 8) W4[(lane + 192) * 4 + wv] = e3 * inv;
        }
        __syncthreads();

        // B: caps partials from registers; only W4 b128 reads touch LDS.
        {
            float4 a0 = make_float4(0,0,0,0), a1 = a0, a2 = a0, a3 = a0;
            #pragma unroll
            for (int i = 0; i < 13; i++) {
                int l  = wv * 50 + i * 4 + q;
                int lc = (l < LSEQ - 1) ? l : (LSEQ - 1);
                float4 w = *(const float4*)(W4 + lc * 4);
                fma4(a0, w.x, hp4[i]); fma4(a1, w.y, hp4[i]);
                fma4(a2, w.z, hp4[i]); fma4(a3, w.w, hp4[i]);
            }
            #pragma unroll
            for (int off = 16; off <= 32; off <<= 1) {
                a0.x += __shfl_xor(a0.x, off, 64); a0.y += __shfl_xor(a0.y, off, 64);
                a0.z += __shfl_xor(a0.z, off, 64); a0.w += __shfl_xor(a0.w, off, 64);
                a1.x += __shfl_xor(a1.x, off, 64); a1.y += __shfl_xor(a1.y, off, 64);
                a1.z += __shfl_xor(a1.z, off, 64); a1.w += __shfl_xor(a1.w, off, 64);
                a2.x += __shfl_xor(a2.x, off, 64); a2.y += __shfl_xor(a2.y, off, 64);
                a2.z += __shfl_xor(a2.z, off, 64); a2.w += __shfl_xor(a2.w, off, 64);
                a3.x += __shfl_xor(a3.x, off, 64); a3.y += __shfl_xor(a3.y, off, 64);
                a3.z += __shfl_xor(a3.z, off, 64); a3.w += __shfl_xor(a3.w, off, 64);
            }
            if (q == 0) {
                part4[(wv * 4 + 0) * 17 + r] = a0;
                part4[(wv * 4 + 1) * 17 + r] = a1;
                part4[(wv * 4 + 2) * 17 + r] = a2;
                part4[(wv * 4 + 3) * 17 + r] = a3;
            }
        }
        __syncthreads();

        // C: reduce wave partials + squash; thread = (k = wv, d = lane)
        {
            const float* pf = (const float*)part4;
            float c = pf[(0 * 4 + wv) * 68 + lane] + pf[(1 * 4 + wv) * 68 + lane]
                    + pf[(2 * 4 + wv) * 68 + lane] + pf[(3 * 4 + wv) * 68 + lane];
            float n2 = c * c;
            #pragma unroll
            for (int off = 32; off; off >>= 1) n2 += __shfl_xor(n2, off, 64);
            float n  = sqrtf(n2);
            float sc = n2 / ((1.f + n2) * n + 1e-9f);
            c *= sc;
            caps4[lane * 4 + wv]             = c;
            ((float*)capsT4)[wv * 64 + lane] = c;
        }
        __syncthreads();

        if (rr < 2) {
            // D: B[k][l] += caps[k].hisP[l] from registers; butterfly over the
            // 16 r-lanes (d-chunks). Exact fp32, zero big-LDS.
            float4 c0 = capsT4[0 * 16 + r];
            float4 c1 = capsT4[1 * 16 + r];
            float4 c2 = capsT4[2 * 16 + r];
            float4 c3 = capsT4[3 * 16 + r];
            #pragma unroll
            for (int i = 0; i < 13; i++) {
                float4 v = hp4[i];
                float p0 = fmaf(v.x, c0.x, fmaf(v.y, c0.y, fmaf(v.z, c0.z, v.w * c0.w)));
                float p1 = fmaf(v.x, c1.x, fmaf(v.y, c1.y, fmaf(v.z, c1.z, v.w * c1.w)));
                float p2 = fmaf(v.x, c2.x, fmaf(v.y, c2.y, fmaf(v.z, c2.z, v.w * c2.w)));
                float p3 = fmaf(v.x, c3.x, fmaf(v.y, c3.y, fmaf(v.z, c3.z, v.w * c3.w)));
                #pragma unroll
                for (int off = 1; off < 16; off <<= 1) {
                    p0 += __shfl_xor(p0, off, 64);
                    p1 += __shfl_xor(p1, off, 64);
                    p2 += __shfl_xor(p2, off, 64);
                    p3 += __shfl_xor(p3, off, 64);
                }
                if (r < 4 && ((i < 12) || (q < 2))) {
                    int l = wv * 50 + i * 4 + q;
                    float p = (r == 0) ? p0 : (r == 1) ? p1 : (r == 2) ? p2 : p3;
                    Bm[r * 200 + l] += p;
                }
            }
            __syncthreads();
        }
    }

    // MLP layer 1: thread = f; h44[f] = relu(caps @ W1 + b1) for 4 capsules.
    {
        const int f = tid;
        float h0 = 0, h1 = 0, h2 = 0, h3 = 0;
        #pragma unroll 8
        for (int d = 0; d < 64; d++) {
            float  w = W1[d * 256 + f];                  // coalesced, L2-hot
            float4 c = *(const float4*)(caps4 + d * 4);  // b128 broadcast
            h0 = fmaf(c.x, w, h0); h1 = fmaf(c.y, w, h1);
            h2 = fmaf(c.z, w, h2); h3 = fmaf(c.w, w, h3);
        }
        float bb = b1[f];
        h44[f] = make_float4(fmaxf(h0 + bb, 0.f), fmaxf(h1 + bb, 0.f),
                             fmaxf(h2 + bb, 0.f), fmaxf(h3 + bb, 0.f));
    }
    __syncthreads();
    float* partf = (float*)part4;                        // 1024 of 1088 floats
    {
        float o0 = 0, o1 = 0, o2 = 0, o3 = 0;
        #pragma unroll 8
        for (int i = 0; i < 64; i++) {
            int f = wv * 64 + i;
            float  w  = W2[f * 64 + lane];               // coalesced, L2-hot
            float4 hv = h44[f];                          // b128 broadcast
            o0 = fmaf(hv.x, w, o0); o1 = fmaf(hv.y, w, o1);
            o2 = fmaf(hv.z, w, o2); o3 = fmaf(hv.w, w, o3);
        }
        partf[wv * 256 + lane]       = o0;
        partf[wv * 256 + 64 + lane]  = o1;
        partf[wv * 256 + 128 + lane] = o2;
        partf[wv * 256 + 192 + lane] = o3;
    }
    __syncthreads();
    {
        float o = partf[wv * 64 + lane]       + partf[256 + wv * 64 + lane]
                + partf[512 + wv * 64 + lane] + partf[768 + wv * 64 + lane];
        out[b * 256 + tid] = o + b2[lane];
    }
}

extern "C" void kernel_launch(void* const* d_in, const int* in_sizes, int n_in,
                              void* d_out, int out_size, void* d_ws, size_t ws_size,
                              hipStream_t stream) {
    const int*   his = (const int*)  d_in[0];
    const float* E   = (const float*)d_in[1];
    const float* S   = (const float*)d_in[2];
    const float* B0  = (const float*)d_in[3];
    const float* W1  = (const float*)d_in[4];
    const float* b1  = (const float*)d_in[5];
    const float* W2  = (const float*)d_in[6];
    const float* b2  = (const float*)d_in[7];
    float* out = (float*)d_out;
    float* P   = (float*)d_ws;                 // NVOC*64 floats = 25.6 MB scratch

    precompute_P<<<(NVOC + 255) / 256, 256, 0, stream>>>(E, S, P);
    mind_row<<<4096, 256, 0, stream>>>(his, P, B0, W1, b1, W2, b2, out);
}

// Round 5
// 254.301 us; speedup vs baseline: 1.1627x; 1.1627x over previous
//
#include <hip/hip_runtime.h>

#define LSEQ 200
#define KCAP 4
#define NVOC 100000

__device__ __forceinline__ void fma4(float4& a, float s, const float4& v) {
    a.x = fmaf(s, v.x, a.x); a.y = fmaf(s, v.y, a.y);
    a.z = fmaf(s, v.z, a.z); a.w = fmaf(s, v.w, a.w);
}

// ---------------------------------------------------------------------------
// Kernel 1: P = (E with row 0 zeroed) @ S.  64 vocab rows/block (lane = row),
// wave = 16-col slice; S in 16KB LDS, wave-uniform b128 broadcasts feeding
// 16 v_fma each. acc = 16 VGPRs -> fits the 64-VGPR cap the 16KB-LDS
// occupancy target (8 blocks/CU) implies. No spill by construction.
// ---------------------------------------------------------------------------
__global__ __launch_bounds__(256)
void precompute_P(const float* __restrict__ E, const float* __restrict__ S,
                  float* __restrict__ P)
{
    __shared__ __align__(16) float4 Sl4[1024];     // S[e][4j..4j+3] = Sl4[e*16+j]
    const int tid = threadIdx.x;
    #pragma unroll
    for (int t = tid; t < 1024; t += 256) Sl4[t] = ((const float4*)S)[t];
    __syncthreads();

    const int lane = tid & 63;
    const int wv   = tid >> 6;                     // column slice [wv*16, wv*16+16)
    const int row  = blockIdx.x * 64 + lane;
    const bool ok  = (row < NVOC);
    const float4* __restrict__ Er = (const float4*)E + (size_t)(ok ? row : 0) * 16;

    float4 acc[4];
    #pragma unroll
    for (int j = 0; j < 4; j++) acc[j] = make_float4(0.f, 0.f, 0.f, 0.f);

    #pragma unroll 2
    for (int ec = 0; ec < 16; ec++) {              // e-chunks of 4
        float4 ev = Er[ec];
        float e4[4] = {ev.x, ev.y, ev.z, ev.w};
        #pragma unroll
        for (int u = 0; u < 4; u++) {
            const float4* Se = Sl4 + (ec * 4 + u) * 16 + wv * 4;  // uniform -> bcast
            fma4(acc[0], e4[u], Se[0]);
            fma4(acc[1], e4[u], Se[1]);
            fma4(acc[2], e4[u], Se[2]);
            fma4(acc[3], e4[u], Se[3]);
        }
    }
    if (ok) {
        float4* Pr = (float4*)P + (size_t)row * 16 + wv * 4;
        if (row == 0) {
            Pr[0] = Pr[1] = Pr[2] = Pr[3] = make_float4(0.f, 0.f, 0.f, 0.f);
        } else {
            Pr[0] = acc[0]; Pr[1] = acc[1]; Pr[2] = acc[2]; Pr[3] = acc[3];
        }
    }
}

// ---------------------------------------------------------------------------
// Kernel 2: one batch row per block. hisP in registers only; phase D via
// 16-lane butterflies. h44 deliberately oversized so static LDS = 38.4 KB:
// the backend's occupancy heuristic then targets 4 blocks/CU -> VGPR budget
// 128 -> no scratch spill (R3/R4's 18.9KB LDS targeted 8 blocks -> 64-VGPR
// cap -> 74MB spill traffic).
// ---------------------------------------------------------------------------
__global__ __launch_bounds__(256, 2)
void mind_row(
    const int*   __restrict__ his, const float* __restrict__ P,
    const float* __restrict__ B0,  const float* __restrict__ W1,
    const float* __restrict__ b1,  const float* __restrict__ W2,
    const float* __restrict__ b2,  float* __restrict__ out)
{
    __shared__ __align__(16) float  W4[LSEQ * 4];       // W4[l*4+k]
    __shared__ __align__(16) float  Bm[KCAP * LSEQ];
    __shared__ __align__(16) float  caps4[64 * 4];      // caps4[d*4+k]
    __shared__ __align__(16) float4 capsT4[KCAP * 16];  // capsT4[k*16+j]
    __shared__ __align__(16) float4 part4[16 * 17];     // [(w*4+k)*17 + r]
    __shared__ __align__(16) float4 h44[1500];          // only [0..255] used; pad
                                                        // sizes LDS for 4 blk/CU
    __shared__ float bigneg[LSEQ];
    __shared__ int   idxs[LSEQ];

    const int b = blockIdx.x, tid = threadIdx.x;
    const int lane = tid & 63, wv = tid >> 6;
    const int q = lane >> 4, r = lane & 15;

    for (int l = tid; l < LSEQ; l += 256) {
        int id = his[b * LSEQ + l];
        idxs[l]   = id;
        bigneg[l] = (id != 0) ? 0.f : -1e30f;
    }
    for (int t = tid; t < KCAP * LSEQ; t += 256) Bm[t] = B0[t];
    __syncthreads();

    // Gather: wave wv covers l in [wv*50, wv*50+50); thread (q,r): l=base+4i+q,
    // d-chunk = r. 13 b128 global loads, registers only.
    float4 hp4[13];
    const float4* P4 = (const float4*)P;
    #pragma unroll
    for (int i = 0; i < 13; i++) {
        int  l     = wv * 50 + i * 4 + q;
        bool valid = (i < 12) || (q < 2);               // 12*4+2 = 50
        int  lc    = valid ? l : 0;
        float4 vv  = P4[(size_t)idxs[lc] * 16 + r];
        if (!valid) vv = make_float4(0.f, 0.f, 0.f, 0.f);
        hp4[i] = vv;
    }

    for (int rr = 0; rr < 3; rr++) {
        // A: masked softmax over l; capsule k = wv (one wave per capsule)
        {
            const float* Bk = Bm + wv * LSEQ;
            float x0 = Bk[lane]       + bigneg[lane];
            float x1 = Bk[lane + 64]  + bigneg[lane + 64];
            float x2 = Bk[lane + 128] + bigneg[lane + 128];
            float x3 = (lane < 8) ? (Bk[lane + 192] + bigneg[lane + 192]) : -3.0e38f;
            float m = fmaxf(fmaxf(x0, x1), fmaxf(x2, x3));
            #pragma unroll
            for (int off = 32; off; off >>= 1) m = fmaxf(m, __shfl_xor(m, off, 64));
            float e0 = __expf(x0 - m), e1 = __expf(x1 - m), e2 = __expf(x2 - m);
            float e3 = (lane < 8) ? __expf(x3 - m) : 0.f;
            float s = e0 + e1 + e2 + e3;
            #pragma unroll
            for (int off = 32; off; off >>= 1) s += __shfl_xor(s, off, 64);
            float inv = 1.f / s;
            W4[lane * 4 + wv]         = e0 * inv;
            W4[(lane + 64) * 4 + wv]  = e1 * inv;
            W4[(lane + 128) * 4 + wv] = e2 * inv;
            if (lane < 8) W4[(lane + 192) * 4 + wv] = e3 * inv;
        }
        __syncthreads();

        // B: caps partials from registers; only W4 b128 reads touch LDS.
        {
            float4 a0 = make_float4(0,0,0,0), a1 = a0, a2 = a0, a3 = a0;
            #pragma unroll
            for (int i = 0; i < 13; i++) {
                int l  = wv * 50 + i * 4 + q;
                int lc = (l < LSEQ - 1) ? l : (LSEQ - 1);
                float4 w = *(const float4*)(W4 + lc * 4);
                fma4(a0, w.x, hp4[i]); fma4(a1, w.y, hp4[i]);
                fma4(a2, w.z, hp4[i]); fma4(a3, w.w, hp4[i]);
            }
            #pragma unroll
            for (int off = 16; off <= 32; off <<= 1) {
                a0.x += __shfl_xor(a0.x, off, 64); a0.y += __shfl_xor(a0.y, off, 64);
                a0.z += __shfl_xor(a0.z, off, 64); a0.w += __shfl_xor(a0.w, off, 64);
                a1.x += __shfl_xor(a1.x, off, 64); a1.y += __shfl_xor(a1.y, off, 64);
                a1.z += __shfl_xor(a1.z, off, 64); a1.w += __shfl_xor(a1.w, off, 64);
                a2.x += __shfl_xor(a2.x, off, 64); a2.y += __shfl_xor(a2.y, off, 64);
                a2.z += __shfl_xor(a2.z, off, 64); a2.w += __shfl_xor(a2.w, off, 64);
                a3.x += __shfl_xor(a3.x, off, 64); a3.y += __shfl_xor(a3.y, off, 64);
                a3.z += __shfl_xor(a3.z, off, 64); a3.w += __shfl_xor(a3.w, off, 64);
            }
            if (q == 0) {
                part4[(wv * 4 + 0) * 17 + r] = a0;
                part4[(wv * 4 + 1) * 17 + r] = a1;
                part4[(wv * 4 + 2) * 17 + r] = a2;
                part4[(wv * 4 + 3) * 17 + r] = a3;
            }
        }
        __syncthreads();

        // C: reduce wave partials + squash; thread = (k = wv, d = lane)
        {
            const float* pf = (const float*)part4;
            float c = pf[(0 * 4 + wv) * 68 + lane] + pf[(1 * 4 + wv) * 68 + lane]
                    + pf[(2 * 4 + wv) * 68 + lane] + pf[(3 * 4 + wv) * 68 + lane];
            float n2 = c * c;
            #pragma unroll
            for (int off = 32; off; off >>= 1) n2 += __shfl_xor(n2, off, 64);
            float n  = sqrtf(n2);
            float sc = n2 / ((1.f + n2) * n + 1e-9f);
            c *= sc;
            caps4[lane * 4 + wv]             = c;
            ((float*)capsT4)[wv * 64 + lane] = c;
        }
        __syncthreads();

        if (rr < 2) {
            // D: B[k][l] += caps[k].hisP[l] from registers; butterfly over the
            // 16 r-lanes (d-chunks). Exact fp32, zero big-LDS.
            float4 c0 = capsT4[0 * 16 + r];
            float4 c1 = capsT4[1 * 16 + r];
            float4 c2 = capsT4[2 * 16 + r];
            float4 c3 = capsT4[3 * 16 + r];
            #pragma unroll
            for (int i = 0; i < 13; i++) {
                float4 v = hp4[i];
                float p0 = fmaf(v.x, c0.x, fmaf(v.y, c0.y, fmaf(v.z, c0.z, v.w * c0.w)));
                float p1 = fmaf(v.x, c1.x, fmaf(v.y, c1.y, fmaf(v.z, c1.z, v.w * c1.w)));
                float p2 = fmaf(v.x, c2.x, fmaf(v.y, c2.y, fmaf(v.z, c2.z, v.w * c2.w)));
                float p3 = fmaf(v.x, c3.x, fmaf(v.y, c3.y, fmaf(v.z, c3.z, v.w * c3.w)));
                #pragma unroll
                for (int off = 1; off < 16; off <<= 1) {
                    p0 += __shfl_xor(p0, off, 64);
                    p1 += __shfl_xor(p1, off, 64);
                    p2 += __shfl_xor(p2, off, 64);
                    p3 += __shfl_xor(p3, off, 64);
                }
                if (r < 4 && ((i < 12) || (q < 2))) {
                    int l = wv * 50 + i * 4 + q;
                    float p = (r == 0) ? p0 : (r == 1) ? p1 : (r == 2) ? p2 : p3;
                    Bm[r * 200 + l] += p;
                }
            }
            __syncthreads();
        }
    }

    // MLP layer 1: thread = f; h44[f] = relu(caps @ W1 + b1) for 4 capsules.
    {
        const int f = tid;
        float h0 = 0, h1 = 0, h2 = 0, h3 = 0;
        #pragma unroll 8
        for (int d = 0; d < 64; d++) {
            float  w = W1[d * 256 + f];                  // coalesced, L2-hot
            float4 c = *(const float4*)(caps4 + d * 4);  // b128 broadcast
            h0 = fmaf(c.x, w, h0); h1 = fmaf(c.y, w, h1);
            h2 = fmaf(c.z, w, h2); h3 = fmaf(c.w, w, h3);
        }
        float bb = b1[f];
        h44[f] = make_float4(fmaxf(h0 + bb, 0.f), fmaxf(h1 + bb, 0.f),
                             fmaxf(h2 + bb, 0.f), fmaxf(h3 + bb, 0.f));
    }
    __syncthreads();
    float* partf = (float*)part4;                        // 1024 of 1088 floats
    {
        float o0 = 0, o1 = 0, o2 = 0, o3 = 0;
        #pragma unroll 8
        for (int i = 0; i < 64; i++) {
            int f = wv * 64 + i;
            float  w  = W2[f * 64 + lane];               // coalesced, L2-hot
            float4 hv = h44[f];                          // b128 broadcast
            o0 = fmaf(hv.x, w, o0); o1 = fmaf(hv.y, w, o1);
            o2 = fmaf(hv.z, w, o2); o3 = fmaf(hv.w, w, o3);
        }
        partf[wv * 256 + lane]       = o0;
        partf[wv * 256 + 64 + lane]  = o1;
        partf[wv * 256 + 128 + lane] = o2;
        partf[wv * 256 + 192 + lane] = o3;
    }
    __syncthreads();
    {
        float o = partf[wv * 64 + lane]       + partf[256 + wv * 64 + lane]
                + partf[512 + wv * 64 + lane] + partf[768 + wv * 64 + lane];
        out[b * 256 + tid] = o + b2[lane];
    }
}

extern "C" void kernel_launch(void* const* d_in, const int* in_sizes, int n_in,
                              void* d_out, int out_size, void* d_ws, size_t ws_size,
                              hipStream_t stream) {
    const int*   his = (const int*)  d_in[0];
    const float* E   = (const float*)d_in[1];
    const float* S   = (const float*)d_in[2];
    const float* B0  = (const float*)d_in[3];
    const float* W1  = (const float*)d_in[4];
    const float* b1  = (const float*)d_in[5];
    const float* W2  = (const float*)d_in[6];
    const float* b2  = (const float*)d_in[7];
    float* out = (float*)d_out;
    float* P   = (float*)d_ws;                 // NVOC*64 floats = 25.6 MB scratch

    precompute_P<<<(NVOC + 63) / 64, 256, 0, stream>>>(E, S, P);
    mind_row<<<4096, 256, 0, stream>>>(his, P, B0, W1, b1, W2, b2, out);
}